// Round 9
// baseline (226.666 us; speedup 1.0000x reference)
//
#include <hip/hip_runtime.h>
#include <math.h>

#define BB 8
#define LL 2048
#define DD 128
#define HH 4
#define DKK 32
#define DFFF 256

#define NEGMIN (-3.402823466e38f)
#define LOG2E 1.44269504088896f

typedef _Float16 f16;
typedef _Float16 f16x4 __attribute__((ext_vector_type(4)));
typedef _Float16 f16x8 __attribute__((ext_vector_type(8)));
typedef __fp16 h16x2 __attribute__((ext_vector_type(2)));
typedef float f32x4 __attribute__((ext_vector_type(4)));

union PKU { h16x2 h2[2]; f16x4 v; };

// ---------------- x -> f16 convert ----------------
__global__ __launch_bounds__(256) void xcvt_kernel(const float* __restrict__ x,
                                                   f16* __restrict__ xh) {
  const int i = (blockIdx.x * 256 + threadIdx.x) * 8;
  float4 v0 = *(const float4*)(x + i);
  float4 v1 = *(const float4*)(x + i + 4);
  f16x8 h;
  h[0] = (f16)v0.x; h[1] = (f16)v0.y; h[2] = (f16)v0.z; h[3] = (f16)v0.w;
  h[4] = (f16)v1.x; h[5] = (f16)v1.y; h[6] = (f16)v1.z; h[7] = (f16)v1.w;
  *(f16x8*)(xh + i) = h;
}

// ---------------- weight convert: all weights -> f16 transposed [n][k] ----
__global__ __launch_bounds__(256) void wconv_kernel(
    const float* __restrict__ Wq, const float* __restrict__ Wk,
    const float* __restrict__ Wv, const float* __restrict__ Wo,
    const float* __restrict__ W1, const float* __restrict__ W2,
    f16* __restrict__ wt) {
  const int idx = blockIdx.x * 256 + threadIdx.x;
  const int i = idx >> 17;
  const int r = idx & 131071;
  float val;
  if (r < 49152) {
    const int sel = r / 16384;
    const int rr = r & 16383;
    const int n = rr >> 7, k = rr & 127;
    const float* W = (sel == 0) ? Wq : (sel == 1) ? Wk : Wv;
    val = W[((size_t)(i * 4 + (n >> 5)) * 128 + k) * 32 + (n & 31)];
  } else if (r < 65536) {
    const int r2 = r - 49152;
    const int n = r2 >> 7, k = r2 & 127;
    val = Wo[i * 16384 + k * 128 + n];
  } else if (r < 98304) {
    const int r2 = r - 65536;
    const int n = r2 >> 7, k = r2 & 127;
    val = W1[i * 32768 + k * 256 + n];
  } else {
    const int r2 = r - 98304;
    const int n = r2 >> 8, k = r2 & 255;
    val = W2[i * 32768 + k * 128 + n];
  }
  wt[idx] = (f16)val;
}

// ---------------- QKV projection via MFMA (layer 0 only) ------------------
__global__ __launch_bounds__(256) void qkv_kernel(
    const f16* __restrict__ xh, const f16* __restrict__ wqkvT,
    f16* __restrict__ qh, f16* __restrict__ kh, f16* __restrict__ vth) {
  const int t = threadIdx.x;
  const int wave = t >> 6, lane = t & 63;
  const int g = lane >> 4, c = lane & 15;
  const int r0g = blockIdx.x * 64 + wave * 16;
  const int b4 = (r0g >> 11) * 4;
  const int l0 = r0g & 2047;

  f16x8 a[4];
#pragma unroll
  for (int kt = 0; kt < 4; ++kt)
    a[kt] = *(const f16x8*)(xh + (size_t)(r0g + c) * 128 + kt * 32 + g * 8);

#pragma unroll
  for (int sel = 0; sel < 2; ++sel) {
    const f16* wT = wqkvT + sel * 16384;
    f16* out = (sel == 0) ? qh : kh;
#pragma unroll
    for (int nt = 0; nt < 8; ++nt) {
      f32x4 acc = {0.f, 0.f, 0.f, 0.f};
#pragma unroll
      for (int kt = 0; kt < 4; ++kt) {
        f16x8 bfrag = *(const f16x8*)(wT + (nt * 16 + c) * 128 + kt * 32 + g * 8);
        acc = __builtin_amdgcn_mfma_f32_16x16x32_f16(a[kt], bfrag, acc, 0, 0, 0);
      }
      const int h = nt >> 1, e = (nt & 1) * 16 + c;
#pragma unroll
      for (int r = 0; r < 4; ++r)
        out[((size_t)(b4 + h) * LL + l0 + 4 * g + r) * DKK + e] = (f16)acc[r];
    }
  }
  {
    const f16* wT = wqkvT + 2 * 16384;
#pragma unroll
    for (int nt = 0; nt < 8; ++nt) {
      f32x4 acc = {0.f, 0.f, 0.f, 0.f};
#pragma unroll
      for (int kt = 0; kt < 4; ++kt) {
        f16x8 afrag = *(const f16x8*)(wT + (nt * 16 + c) * 128 + kt * 32 + g * 8);
        acc = __builtin_amdgcn_mfma_f32_16x16x32_f16(afrag, a[kt], acc, 0, 0, 0);
      }
#pragma unroll
      for (int r = 0; r < 4; ++r) {
        const int eg = nt * 16 + 4 * g + r;
        vth[((size_t)(b4 + (eg >> 5)) * DKK + (eg & 31)) * LL + l0 + c] =
            (f16)acc[r];
      }
    }
  }
}

// ---------------- Flash attention: 16 q/wave, 64 q/block, l via MFMA -----
__global__ __launch_bounds__(256) void attn_kernel(
    const f16* __restrict__ qh, const f16* __restrict__ kh,
    const f16* __restrict__ vth, const float* __restrict__ mask,
    f16* __restrict__ o) {
  __shared__ f16 Ks[2][64][40];
  __shared__ f16 Vt[2][32][72];
  __shared__ float mks[2][64];
  __shared__ int mkflag[2];
  const int t = threadIdx.x;
  const int wave = t >> 6, lane = t & 63;
  const int g = lane >> 4, c = lane & 15;

  // XCD-aware remap: 1024 blocks, 128 per XCD, 32 q-blocks of one bh together
  const int flat = blockIdx.y * 32 + blockIdx.x;
  const int xcd = flat & 7, slot = flat >> 3;
  const int bh = xcd * 4 + (slot >> 5);
  const int qb = slot & 31;
  const int b = bh >> 2;
  const int qw = qb * 64 + wave * 16;

  const f16x8 qfrag =
      *(const f16x8*)(qh + ((size_t)bh * LL + qw + c) * DKK + g * 8);
  const float mqv = mask[b * LL + qw + c];
  const bool qflag = __all(mqv == 1.f);

  f32x4 o4[2], lacc;
  float m = -3.0e38f;
#pragma unroll
  for (int r = 0; r < 4; ++r) { o4[0][r] = 0.f; o4[1][r] = 0.f; lacc[r] = 0.f; }
  f16x4 ones;
  ones[0] = (f16)1.f; ones[1] = (f16)1.f; ones[2] = (f16)1.f; ones[3] = (f16)1.f;

  const f16* kbase = kh + (size_t)bh * LL * DKK;
  const f16* vbase = vth + (size_t)bh * DKK * LL;
  const int krow = t >> 2, kch = t & 3;
  const int vd = t >> 3, vseg = t & 7;

  f16x8 kreg = *(const f16x8*)(kbase + (size_t)krow * DKK + kch * 8);
  f16x8 vreg = *(const f16x8*)(vbase + (size_t)vd * LL + vseg * 8);
  float mreg = (t < 64) ? mask[b * LL + t] : 1.f;
  *(f16x8*)&Ks[0][krow][kch * 8] = kreg;
  *(f16x8*)&Vt[0][vd][vseg * 8] = vreg;
  if (t < 64) mks[0][t] = mreg;
  if (wave == 0) {
    unsigned long long ok = __ballot(mreg == 1.f);
    if (lane == 0) mkflag[0] = (ok == ~0ull);
  }
  __syncthreads();

  for (int kt = 0; kt < LL / 64; ++kt) {
    const int cur = kt & 1;
    if (kt < LL / 64 - 1) {
      const int k0 = (kt + 1) * 64;
      kreg = *(const f16x8*)(kbase + (size_t)(k0 + krow) * DKK + kch * 8);
      vreg = *(const f16x8*)(vbase + (size_t)vd * LL + k0 + vseg * 8);
      mreg = (t < 64) ? mask[b * LL + k0 + t] : 1.f;
    }
    const bool nomask = qflag && mkflag[cur];

    // ---- fragments ----
    f16x8 kb[4];
#pragma unroll
    for (int nt = 0; nt < 4; ++nt)
      kb[nt] = *(const f16x8*)&Ks[cur][nt * 16 + c][g * 8];
    f16x4 va[2][4];
#pragma unroll
    for (int dt = 0; dt < 2; ++dt)
#pragma unroll
      for (int nt = 0; nt < 4; ++nt)
        va[dt][nt] = *(const f16x4*)&Vt[cur][dt * 16 + c][nt * 16 + 4 * g];

    // ---- QK^T (MFMA cluster): S^T[kv=16nt+4g+r][q=c] ----
    f32x4 st[4];
    __builtin_amdgcn_s_setprio(1);
#pragma unroll
    for (int nt = 0; nt < 4; ++nt) {
      f32x4 z = {0.f, 0.f, 0.f, 0.f};
      st[nt] =
          __builtin_amdgcn_mfma_f32_16x16x32_f16(kb[nt], qfrag, z, 0, 0, 0);
    }
    __builtin_amdgcn_s_setprio(0);

    if (!nomask) {
#pragma unroll
      for (int nt = 0; nt < 4; ++nt) {
        float4 mk4 = *(const float4*)&mks[cur][nt * 16 + 4 * g];
        st[nt][0] += (1.f - mqv * mk4.x) * NEGMIN;
        st[nt][1] += (1.f - mqv * mk4.y) * NEGMIN;
        st[nt][2] += (1.f - mqv * mk4.z) * NEGMIN;
        st[nt][3] += (1.f - mqv * mk4.w) * NEGMIN;
      }
    }

    // ---- row max: 15 fmax + 2 shfl ----
    float vmax = fmaxf(fmaxf(st[0][0], st[0][1]), fmaxf(st[0][2], st[0][3]));
#pragma unroll
    for (int nt = 1; nt < 4; ++nt)
      vmax = fmaxf(vmax, fmaxf(fmaxf(st[nt][0], st[nt][1]),
                               fmaxf(st[nt][2], st[nt][3])));
    vmax = fmaxf(vmax, __shfl_xor(vmax, 16));
    vmax = fmaxf(vmax, __shfl_xor(vmax, 32));

    // ---- defer-max: rescale only when growth > 8 ----
    if (!__all(vmax - m <= 8.f)) {
      const float mn = fmaxf(m, vmax);
      const float sc = __builtin_exp2f((m - mn) * LOG2E);
#pragma unroll
      for (int r = 0; r < 4; ++r) {
        o4[0][r] *= sc; o4[1][r] *= sc; lacc[r] *= sc;
      }
      m = mn;
    }
    const float mn2 = m * LOG2E;

    // ---- exp + pack + PV + l (MFMA cluster) ----
    PKU pk[4];
#pragma unroll
    for (int nt = 0; nt < 4; ++nt) {
      float p0 = __builtin_exp2f(fmaf(st[nt][0], LOG2E, -mn2));
      float p1 = __builtin_exp2f(fmaf(st[nt][1], LOG2E, -mn2));
      float p2 = __builtin_exp2f(fmaf(st[nt][2], LOG2E, -mn2));
      float p3 = __builtin_exp2f(fmaf(st[nt][3], LOG2E, -mn2));
      pk[nt].h2[0] = __builtin_amdgcn_cvt_pkrtz(p0, p1);
      pk[nt].h2[1] = __builtin_amdgcn_cvt_pkrtz(p2, p3);
    }
    __builtin_amdgcn_s_setprio(1);
#pragma unroll
    for (int nt = 0; nt < 4; ++nt) {
      o4[0] = __builtin_amdgcn_mfma_f32_16x16x16f16(va[0][nt], pk[nt].v,
                                                    o4[0], 0, 0, 0);
      o4[1] = __builtin_amdgcn_mfma_f32_16x16x16f16(va[1][nt], pk[nt].v,
                                                    o4[1], 0, 0, 0);
      lacc = __builtin_amdgcn_mfma_f32_16x16x16f16(ones, pk[nt].v,
                                                   lacc, 0, 0, 0);
    }
    __builtin_amdgcn_s_setprio(0);

    if (kt < LL / 64 - 1) {
      *(f16x8*)&Ks[1 - cur][krow][kch * 8] = kreg;
      *(f16x8*)&Vt[1 - cur][vd][vseg * 8] = vreg;
      if (t < 64) mks[1 - cur][t] = mreg;
      if (wave == 0) {
        unsigned long long ok = __ballot(mreg == 1.f);
        if (lane == 0) mkflag[1 - cur] = (ok == ~0ull);
      }
    }
    __syncthreads();
  }

  // ---- epilogue: lacc rows all equal l (no reduce needed) ----
  const int h = bh & 3;
  const float rdiv = 1.f / lacc[0];
  f16* orow = o + ((size_t)b * LL + qw + c) * DD + h * DKK;
#pragma unroll
  for (int dt = 0; dt < 2; ++dt) {
    f16x4 res;
    res[0] = (f16)(o4[dt][0] * rdiv);
    res[1] = (f16)(o4[dt][1] * rdiv);
    res[2] = (f16)(o4[dt][2] * rdiv);
    res[3] = (f16)(o4[dt][3] * rdiv);
    *(f16x4*)(orow + dt * 16 + g * 4) = res;
  }
}

// ---------------- MFMA MLP (+ optional fused next-layer QKV) --------------
__global__ __launch_bounds__(256) void mlp_kernel(
    const f16* __restrict__ o, const float* __restrict__ x,
    const f16* __restrict__ WoT, const f16* __restrict__ W1T,
    const f16* __restrict__ W2T, const float* __restrict__ b1,
    const float* __restrict__ b2, float* __restrict__ xout,
    const f16* __restrict__ wqkvT_next,
    f16* __restrict__ qh, f16* __restrict__ kh, f16* __restrict__ vth) {
  __shared__ f16 Xm[64][136];
  __shared__ f16 Fs[64][264];
  const int t = threadIdx.x;
  const int wave = t >> 6, lane = t & 63;
  const int g = lane >> 4, c = lane & 15;
  const int mrow = wave * 16;
  const long r0 = (long)blockIdx.x * 64;

  // ---- step1: xm = (o @ Wo + x) * 0.5 ----
  f16x8 a1[4];
#pragma unroll
  for (int kt = 0; kt < 4; ++kt)
    a1[kt] = *(const f16x8*)(o + (r0 + mrow + c) * 128 + kt * 32 + g * 8);

  f32x4 xmreg[8];
#pragma unroll
  for (int nt = 0; nt < 8; ++nt) {
    f32x4 acc = {0.f, 0.f, 0.f, 0.f};
#pragma unroll
    for (int kt = 0; kt < 4; ++kt) {
      f16x8 bfrag = *(const f16x8*)(WoT + (nt * 16 + c) * 128 + kt * 32 + g * 8);
      acc = __builtin_amdgcn_mfma_f32_16x16x32_f16(a1[kt], bfrag, acc, 0, 0, 0);
    }
#pragma unroll
    for (int r = 0; r < 4; ++r) {
      const float xv = x[(r0 + mrow + 4 * g + r) * 128 + nt * 16 + c];
      acc[r] = (acc[r] + xv) * 0.5f;
      Xm[mrow + 4 * g + r][nt * 16 + c] = (f16)acc[r];
    }
    xmreg[nt] = acc;
  }

  // ---- step2: f = gelu(xm @ W1 + b1) ----
  f16x8 a2[4];
#pragma unroll
  for (int kt = 0; kt < 4; ++kt)
    a2[kt] = *(const f16x8*)&Xm[mrow + c][kt * 32 + g * 8];
#pragma unroll
  for (int nt = 0; nt < 16; ++nt) {
    f32x4 acc = {0.f, 0.f, 0.f, 0.f};
#pragma unroll
    for (int kt = 0; kt < 4; ++kt) {
      f16x8 bfrag = *(const f16x8*)(W1T + (nt * 16 + c) * 128 + kt * 32 + g * 8);
      acc = __builtin_amdgcn_mfma_f32_16x16x32_f16(a2[kt], bfrag, acc, 0, 0, 0);
    }
    const float bj = b1[nt * 16 + c];
#pragma unroll
    for (int r = 0; r < 4; ++r) {
      const float val = acc[r] + bj;
      Fs[mrow + 4 * g + r][nt * 16 + c] =
          (f16)(0.5f * val * (1.f + erff(val * 0.70710678118654752f)));
    }
  }

  // ---- step3: out = (f @ W2 + b2 + xm) * 0.5 ----
  f16x8 a3[8];
#pragma unroll
  for (int kt = 0; kt < 8; ++kt)
    a3[kt] = *(const f16x8*)&Fs[mrow + c][kt * 32 + g * 8];
#pragma unroll
  for (int nt = 0; nt < 8; ++nt) {
    f32x4 acc = {0.f, 0.f, 0.f, 0.f};
#pragma unroll
    for (int kt = 0; kt < 8; ++kt) {
      f16x8 bfrag = *(const f16x8*)(W2T + (nt * 16 + c) * 256 + kt * 32 + g * 8);
      acc = __builtin_amdgcn_mfma_f32_16x16x32_f16(a3[kt], bfrag, acc, 0, 0, 0);
    }
    const float bj = b2[nt * 16 + c];
#pragma unroll
    for (int r = 0; r < 4; ++r) {
      const float val = (acc[r] + bj + xmreg[nt][r]) * 0.5f;
      xout[(r0 + mrow + 4 * g + r) * 128 + nt * 16 + c] = val;
      Xm[mrow + 4 * g + r][nt * 16 + c] = (f16)val;  // reuse Xm as xh_next
    }
  }

  // ---- step4 (optional): next layer's QKV from Xm (wave-local rows) ----
  if (wqkvT_next) {
    const int r0g = (int)r0 + mrow;
    const int b4 = (r0g >> 11) * 4;
    const int l0 = r0g & 2047;
    f16x8 a[4];
#pragma unroll
    for (int kt = 0; kt < 4; ++kt)
      a[kt] = *(const f16x8*)&Xm[mrow + c][kt * 32 + g * 8];

#pragma unroll
    for (int sel = 0; sel < 2; ++sel) {
      const f16* wT = wqkvT_next + sel * 16384;
      f16* out = (sel == 0) ? qh : kh;
#pragma unroll
      for (int nt = 0; nt < 8; ++nt) {
        f32x4 acc = {0.f, 0.f, 0.f, 0.f};
#pragma unroll
        for (int kt = 0; kt < 4; ++kt) {
          f16x8 bfrag =
              *(const f16x8*)(wT + (nt * 16 + c) * 128 + kt * 32 + g * 8);
          acc = __builtin_amdgcn_mfma_f32_16x16x32_f16(a[kt], bfrag, acc, 0, 0, 0);
        }
        const int h = nt >> 1, e = (nt & 1) * 16 + c;
#pragma unroll
        for (int r = 0; r < 4; ++r)
          out[((size_t)(b4 + h) * LL + l0 + 4 * g + r) * DKK + e] = (f16)acc[r];
      }
    }
    {
      const f16* wT = wqkvT_next + 2 * 16384;
#pragma unroll
      for (int nt = 0; nt < 8; ++nt) {
        f32x4 acc = {0.f, 0.f, 0.f, 0.f};
#pragma unroll
        for (int kt = 0; kt < 4; ++kt) {
          f16x8 afrag =
              *(const f16x8*)(wT + (nt * 16 + c) * 128 + kt * 32 + g * 8);
          acc = __builtin_amdgcn_mfma_f32_16x16x32_f16(afrag, a[kt], acc, 0, 0, 0);
        }
#pragma unroll
        for (int r = 0; r < 4; ++r) {
          const int eg = nt * 16 + 4 * g + r;
          vth[((size_t)(b4 + (eg >> 5)) * DKK + (eg & 31)) * LL + l0 + c] =
              (f16)acc[r];
        }
      }
    }
  }
}

extern "C" void kernel_launch(void* const* d_in, const int* in_sizes, int n_in,
                              void* d_out, int out_size, void* d_ws,
                              size_t ws_size, hipStream_t stream) {
  const float* x    = (const float*)d_in[0];
  const float* mask = (const float*)d_in[1];
  const float* Wq   = (const float*)d_in[2];
  const float* Wk   = (const float*)d_in[3];
  const float* Wv   = (const float*)d_in[4];
  const float* Wo   = (const float*)d_in[5];
  const float* W1   = (const float*)d_in[6];
  const float* b1   = (const float*)d_in[7];
  const float* W2   = (const float*)d_in[8];
  const float* b2   = (const float*)d_in[9];

  const size_t SZ = (size_t)BB * LL * DD;
  char* p = (char*)d_ws;
  f16* qh   = (f16*)p;  p += SZ * sizeof(f16);
  f16* kh   = (f16*)p;  p += SZ * sizeof(f16);
  f16* vth  = (f16*)p;  p += SZ * sizeof(f16);
  f16* ob   = (f16*)p;  p += SZ * sizeof(f16);
  f16* xh0  = (f16*)p;  p += SZ * sizeof(f16);
  f16* wt   = (f16*)p;  p += (size_t)262144 * sizeof(f16);
  float* xA = (float*)p;

  wconv_kernel<<<1024, 256, 0, stream>>>(Wq, Wk, Wv, Wo, W1, W2, wt);
  xcvt_kernel<<<SZ / 8 / 256, 256, 0, stream>>>(x, xh0);

  for (int i = 0; i < 2; ++i) {
    const float* xin = (i == 0) ? x : xA;
    float* xout = (i == 1) ? (float*)d_out : xA;
    const f16* qkvT_i = wt + (size_t)i * 131072;
    const f16* WoT_i  = wt + (size_t)i * 131072 + 49152;
    const f16* W1T_i  = wt + (size_t)i * 131072 + 65536;
    const f16* W2T_i  = wt + (size_t)i * 131072 + 98304;
    const float* b1_i = b1 + (long)i * DFFF;
    const float* b2_i = b2 + (long)i * DD;
    const f16* qkvT_next = (i == 0) ? (wt + 131072) : nullptr;

    if (i == 0)
      qkv_kernel<<<(BB * LL) / 64, 256, 0, stream>>>(xh0, qkvT_i, qh, kh, vth);
    attn_kernel<<<dim3(LL / 64, BB * HH), 256, 0, stream>>>(qh, kh, vth, mask, ob);
    mlp_kernel<<<(BB * LL) / 64, 256, 0, stream>>>(ob, xin, WoT_i, W1T_i, W2T_i,
                                                   b1_i, b2_i, xout,
                                                   qkvT_next, qh, kh, vth);
  }
}